// Round 1
// baseline (1908.346 us; speedup 1.0000x reference)
//
#include <hip/hip_runtime.h>
#include <hip/hip_bf16.h>
#include <math.h>

// Problem constants (from reference): N=100000, E=3200000, F_IN=512, H=16, C=40
#define F_IN 512
#define H 16

// ---------------- degree / norm precompute ----------------

__global__ void deg_kernel(const int* __restrict__ col, const float* __restrict__ ew,
                           float* __restrict__ deg, int E) {
    int e = blockIdx.x * 256 + threadIdx.x;
    if (e < E) atomicAdd(&deg[col[e]], ew[e]);
}

__global__ void dinv_kernel(const float* __restrict__ deg, float* __restrict__ dinv, int N) {
    int n = blockIdx.x * 256 + threadIdx.x;
    if (n < N) {
        float d = deg[n] + 1.0f;  // self-loop weight 1 added to degree
        dinv[n] = d > 0.f ? rsqrtf(d) : 0.f;
    }
}

__global__ void norm_kernel(const int* __restrict__ row, const int* __restrict__ col,
                            const float* __restrict__ ew, const float* __restrict__ dinv,
                            float* __restrict__ norm, int E) {
    int e = blockIdx.x * 256 + threadIdx.x;
    if (e < E) norm[e] = dinv[row[e]] * ew[e] * dinv[col[e]];
}

// ---------------- layer 1: h0 = relu(x @ W_first + b_first) ----------------
// Block = 256 threads = 16 f-groups x 16 outputs. Each lane holds 32 W floats in
// registers (its f-chunk x its output column). x rows staged in LDS with chunk
// stride 36 floats (4-float pad per 32) -> conflict-free ds_read_b128.

#define L1_ROWS 8
#define XS_CH 36
#define XS_ROW (16 * XS_CH)  // 576 floats per row

__global__ __launch_bounds__(256) void l1_kernel(const float* __restrict__ x,
                                                 const float* __restrict__ W,
                                                 const float* __restrict__ b,
                                                 float* __restrict__ h0, int N) {
    __shared__ float xs[L1_ROWS][XS_ROW];     // 18432 B
    __shared__ float part[L1_ROWS][256];      // 8192 B
    const int t  = threadIdx.x;
    const int o  = t & 15;    // output column
    const int fg = t >> 4;    // f-group 0..15 (32 features each)

    float Wreg[32];
#pragma unroll
    for (int j = 0; j < 32; ++j) Wreg[j] = W[(fg * 32 + j) * H + o];
    const float bias = b[o];

    const int nbatch = (N + L1_ROWS - 1) / L1_ROWS;
    for (int batch = blockIdx.x; batch < nbatch; batch += gridDim.x) {
        const int row0 = batch * L1_ROWS;
        // stage 8 rows (1024 float4 loads / 256 threads = 4 each), coalesced
#pragma unroll
        for (int bq = 0; bq < 4; ++bq) {
            int L  = bq * 256 + t;       // float4 index 0..1023
            int rl = L >> 7;             // local row (128 float4 per row)
            int f4 = L & 127;
            int r  = row0 + rl;
            float4 v = make_float4(0.f, 0.f, 0.f, 0.f);
            if (r < N) v = *(const float4*)&x[(size_t)r * F_IN + f4 * 4];
            int fgs = f4 >> 3, j4 = f4 & 7;
            *(float4*)&xs[rl][fgs * XS_CH + j4 * 4] = v;
        }
        __syncthreads();

        float acc[L1_ROWS];
#pragma unroll
        for (int r = 0; r < L1_ROWS; ++r) acc[r] = 0.f;
#pragma unroll
        for (int j4 = 0; j4 < 8; ++j4) {
#pragma unroll
            for (int r = 0; r < L1_ROWS; ++r) {
                float4 xv = *(const float4*)&xs[r][fg * XS_CH + j4 * 4];
                acc[r] = fmaf(xv.x, Wreg[j4 * 4 + 0], acc[r]);
                acc[r] = fmaf(xv.y, Wreg[j4 * 4 + 1], acc[r]);
                acc[r] = fmaf(xv.z, Wreg[j4 * 4 + 2], acc[r]);
                acc[r] = fmaf(xv.w, Wreg[j4 * 4 + 3], acc[r]);
            }
        }
#pragma unroll
        for (int r = 0; r < L1_ROWS; ++r) part[r][fg * 16 + o] = acc[r];
        __syncthreads();

        if (t < 128) {  // 8 rows x 16 outputs
            int r = t >> 4, oo = t & 15;  // oo == o for these threads
            float s = 0.f;
#pragma unroll
            for (int g = 0; g < 16; ++g) s += part[r][g * 16 + oo];
            s = fmaxf(s + bias, 0.f);
            int rr = row0 + r;
            if (rr < N) h0[(size_t)rr * H + oo] = s;
        }
        __syncthreads();
    }
}

// ---------------- conv: hW = h_in @ W ; aggr init = dinv^2 * hW (self-loop) ----------------

__global__ __launch_bounds__(256) void mm16_kernel(const float* __restrict__ hin,
                                                   const float* __restrict__ W,
                                                   const float* __restrict__ dinv,
                                                   float* __restrict__ hW,
                                                   float* __restrict__ aggr, int N) {
    __shared__ float Wl[H * H];
    if (threadIdx.x < H * H) Wl[threadIdx.x] = W[threadIdx.x];
    __syncthreads();
    int n = blockIdx.x * 256 + threadIdx.x;
    if (n >= N) return;
    float hv[H];
#pragma unroll
    for (int k4 = 0; k4 < 4; ++k4) {
        float4 v = *(const float4*)&hin[(size_t)n * H + k4 * 4];
        hv[k4 * 4 + 0] = v.x; hv[k4 * 4 + 1] = v.y;
        hv[k4 * 4 + 2] = v.z; hv[k4 * 4 + 3] = v.w;
    }
    float acc[H];
#pragma unroll
    for (int c = 0; c < H; ++c) acc[c] = 0.f;
#pragma unroll
    for (int k = 0; k < H; ++k) {
#pragma unroll
        for (int c = 0; c < H; ++c) acc[c] = fmaf(hv[k], Wl[k * H + c], acc[c]);
    }
    float di = dinv[n];
    float s  = di * di;
#pragma unroll
    for (int c4 = 0; c4 < 4; ++c4) {
        float4 a = make_float4(acc[c4 * 4], acc[c4 * 4 + 1], acc[c4 * 4 + 2], acc[c4 * 4 + 3]);
        *(float4*)&hW[(size_t)n * H + c4 * 4] = a;
        float4 bb = make_float4(s * a.x, s * a.y, s * a.z, s * a.w);
        *(float4*)&aggr[(size_t)n * H + c4 * 4] = bb;
    }
}

// ---------------- edge scatter: aggr[col] += norm_e * hW[row] ----------------
// 4 threads per edge, each handles 4 features (float4 gather + 4 atomics)

__global__ __launch_bounds__(256) void scatter_kernel(const int* __restrict__ row,
                                                      const int* __restrict__ col,
                                                      const float* __restrict__ norm,
                                                      const float* __restrict__ hW,
                                                      float* __restrict__ aggr, int E) {
    long long tid = (long long)blockIdx.x * 256 + threadIdx.x;
    int e = (int)(tid >> 2);
    if (e >= E) return;
    int part = (int)(tid & 3);
    int r = row[e], c = col[e];
    float v = norm[e];
    float4 h = *(const float4*)&hW[(size_t)r * H + part * 4];
    float* dst = &aggr[(size_t)c * H + part * 4];
    atomicAdd(dst + 0, v * h.x);
    atomicAdd(dst + 1, v * h.y);
    atomicAdd(dst + 2, v * h.z);
    atomicAdd(dst + 3, v * h.w);
}

__global__ void bias_relu_kernel(const float* __restrict__ aggr, const float* __restrict__ b,
                                 float* __restrict__ out, int total) {
    int i = blockIdx.x * 256 + threadIdx.x;
    if (i < total) out[i] = fmaxf(aggr[i] + b[i & (H - 1)], 0.f);
}

// ---------------- output layer: log_softmax(h @ W_out + b_out) ----------------

__global__ __launch_bounds__(256) void out_kernel(const float* __restrict__ h,
                                                  const float* __restrict__ W,
                                                  const float* __restrict__ b,
                                                  float* __restrict__ out, int N, int C) {
    extern __shared__ float sm[];         // H*C + C floats
    float* Wl = sm;
    float* bl = sm + H * C;
    for (int i = threadIdx.x; i < H * C; i += 256) Wl[i] = W[i];
    if (threadIdx.x < C) bl[threadIdx.x] = b[threadIdx.x];
    __syncthreads();
    int n = blockIdx.x * 256 + threadIdx.x;
    if (n >= N) return;
    float hv[H];
#pragma unroll
    for (int k4 = 0; k4 < 4; ++k4) {
        float4 v = *(const float4*)&h[(size_t)n * H + k4 * 4];
        hv[k4 * 4 + 0] = v.x; hv[k4 * 4 + 1] = v.y;
        hv[k4 * 4 + 2] = v.z; hv[k4 * 4 + 3] = v.w;
    }
    float acc[40];
    for (int c = 0; c < C; ++c) acc[c] = bl[c];
    for (int k = 0; k < H; ++k) {
        float xk = hv[k];
        for (int c = 0; c < C; ++c) acc[c] = fmaf(xk, Wl[k * C + c], acc[c]);
    }
    float m = -1e30f;
    for (int c = 0; c < C; ++c) m = fmaxf(m, acc[c]);
    float s = 0.f;
    for (int c = 0; c < C; ++c) s += __expf(acc[c] - m);
    float lse = m + __logf(s);
    for (int c = 0; c < C; ++c) acc[c] -= lse;
    // C=40 -> 10 float4 stores, 16B aligned (n*40*4 = n*160, 160 % 16 == 0)
    for (int c4 = 0; c4 < C / 4; ++c4) {
        float4 v = make_float4(acc[c4 * 4], acc[c4 * 4 + 1], acc[c4 * 4 + 2], acc[c4 * 4 + 3]);
        *(float4*)&out[(size_t)n * C + c4 * 4] = v;
    }
}

// ---------------- launch ----------------

extern "C" void kernel_launch(void* const* d_in, const int* in_sizes, int n_in,
                              void* d_out, int out_size, void* d_ws, size_t ws_size,
                              hipStream_t stream) {
    const float* x       = (const float*)d_in[0];
    const int*   ei      = (const int*)d_in[1];
    const float* ew      = (const float*)d_in[2];
    const float* W_first = (const float*)d_in[3];
    const float* b_first = (const float*)d_in[4];
    const float* W_c1    = (const float*)d_in[5];
    const float* b_c1    = (const float*)d_in[6];
    const float* W_c2    = (const float*)d_in[7];
    const float* b_c2    = (const float*)d_in[8];
    const float* W_o     = (const float*)d_in[9];
    const float* b_o     = (const float*)d_in[10];

    const int N = in_sizes[0] / F_IN;
    const int E = in_sizes[2];
    const int C = in_sizes[10];

    const int* row = ei;      // edge_index[0] = source
    const int* col = ei + E;  // edge_index[1] = target

    float* ws   = (float*)d_ws;
    float* deg  = ws;                 // N
    float* dinv = deg + N;            // N
    float* nrm  = dinv + N;           // E
    float* bufA = nrm + E;            // N*H  (h0 / h_layer)
    float* bufB = bufA + (size_t)N * H;  // N*H  (hW)
    float* bufC = bufB + (size_t)N * H;  // N*H  (aggr)

    hipMemsetAsync(deg, 0, (size_t)N * sizeof(float), stream);
    deg_kernel<<<(E + 255) / 256, 256, 0, stream>>>(col, ew, deg, E);
    dinv_kernel<<<(N + 255) / 256, 256, 0, stream>>>(deg, dinv, N);
    norm_kernel<<<(E + 255) / 256, 256, 0, stream>>>(row, col, ew, dinv, nrm, E);

    l1_kernel<<<1024, 256, 0, stream>>>(x, W_first, b_first, bufA, N);

    // conv1
    mm16_kernel<<<(N + 255) / 256, 256, 0, stream>>>(bufA, W_c1, dinv, bufB, bufC, N);
    scatter_kernel<<<(int)(((long long)E * 4 + 255) / 256), 256, 0, stream>>>(row, col, nrm, bufB, bufC, E);
    bias_relu_kernel<<<(N * H + 255) / 256, 256, 0, stream>>>(bufC, b_c1, bufA, N * H);

    // conv2
    mm16_kernel<<<(N + 255) / 256, 256, 0, stream>>>(bufA, W_c2, dinv, bufB, bufC, N);
    scatter_kernel<<<(int)(((long long)E * 4 + 255) / 256), 256, 0, stream>>>(row, col, nrm, bufB, bufC, E);
    bias_relu_kernel<<<(N * H + 255) / 256, 256, 0, stream>>>(bufC, b_c2, bufA, N * H);

    // output + log_softmax
    size_t smem = (size_t)(H * C + C) * sizeof(float);
    out_kernel<<<(N + 255) / 256, 256, smem, stream>>>(bufA, W_o, b_o, (float*)d_out, N, C);
}

// Round 2
// 860.707 us; speedup vs baseline: 2.2172x; 2.2172x over previous
//
#include <hip/hip_runtime.h>
#include <hip/hip_bf16.h>
#include <math.h>

// Problem constants: N=100000, E=3200000, F_IN=512, H=16, C=40
#define F_IN 512
#define H 16

// ---------------- CSR build: counts -> scan -> place ----------------

__global__ void cnt_kernel(const int* __restrict__ col, int* __restrict__ cnt, int E) {
    int e = blockIdx.x * 256 + threadIdx.x;
    if (e < E) atomicAdd(&cnt[col[e]], 1);
}

__global__ void bsum_kernel(const int* __restrict__ cnt, int* __restrict__ bsum, int N) {
    int i = blockIdx.x * 256 + threadIdx.x;
    int v = (i < N) ? cnt[i] : 0;
#pragma unroll
    for (int o = 32; o > 0; o >>= 1) v += __shfl_down(v, o);
    __shared__ int ws[4];
    if ((threadIdx.x & 63) == 0) ws[threadIdx.x >> 6] = v;
    __syncthreads();
    if (threadIdx.x == 0) bsum[blockIdx.x] = ws[0] + ws[1] + ws[2] + ws[3];
}

// single block, 512 threads: in-place exclusive scan of NB (<512) block sums
__global__ void scan_bsum_kernel(int* __restrict__ bsum, int NB) {
    __shared__ int sm[512];
    int t = threadIdx.x;
    sm[t] = (t < NB) ? bsum[t] : 0;
    __syncthreads();
    for (int o = 1; o < 512; o <<= 1) {
        int v = (t >= o) ? sm[t - o] : 0;
        __syncthreads();
        sm[t] += v;
        __syncthreads();
    }
    if (t < NB) bsum[t] = (t > 0) ? sm[t - 1] : 0;
}

__global__ void rowptr_kernel(const int* __restrict__ cnt, const int* __restrict__ bsum,
                              int* __restrict__ rowptr, int N, int E) {
    __shared__ int sm[256];
    int i = blockIdx.x * 256 + threadIdx.x;
    int t = threadIdx.x;
    int v = (i < N) ? cnt[i] : 0;
    sm[t] = v;
    __syncthreads();
    for (int o = 1; o < 256; o <<= 1) {
        int u = (t >= o) ? sm[t - o] : 0;
        __syncthreads();
        sm[t] += u;
        __syncthreads();
    }
    int excl = sm[t] - v;  // inclusive - self
    if (i < N) rowptr[i] = bsum[blockIdx.x] + excl;
    if (i == 0) rowptr[N] = E;
}

__global__ void place_kernel(const int* __restrict__ row, const int* __restrict__ col,
                             const float* __restrict__ ew, const int* __restrict__ rowptr,
                             int* __restrict__ fill, int2* __restrict__ packed, int E) {
    int e = blockIdx.x * 256 + threadIdx.x;
    if (e >= E) return;
    int c = col[e];
    int pos = rowptr[c] + atomicAdd(&fill[c], 1);
    packed[pos] = make_int2(row[e], __float_as_int(ew[e]));
}

// deg[n] = 1 (self loop) + sum of ew in segment -> dinv = rsqrt
__global__ void segdeg_kernel(const int* __restrict__ rowptr, const int2* __restrict__ packed,
                              float* __restrict__ dinv, int N) {
    int n = blockIdx.x * 256 + threadIdx.x;
    if (n >= N) return;
    int s = rowptr[n], e = rowptr[n + 1];
    float d = 1.0f;
    for (int i = s; i < e; ++i) d += __int_as_float(packed[i].y);
    dinv[n] = rsqrtf(d);
}

// ---------------- layer 1: h0 = relu(x @ W_first + b_first) ----------------

#define L1_ROWS 8
#define XS_CH 36
#define XS_ROW (16 * XS_CH)

__global__ __launch_bounds__(256) void l1_kernel(const float* __restrict__ x,
                                                 const float* __restrict__ W,
                                                 const float* __restrict__ b,
                                                 float* __restrict__ h0, int N) {
    __shared__ float xs[L1_ROWS][XS_ROW];
    __shared__ float part[L1_ROWS][256];
    const int t  = threadIdx.x;
    const int o  = t & 15;
    const int fg = t >> 4;

    float Wreg[32];
#pragma unroll
    for (int j = 0; j < 32; ++j) Wreg[j] = W[(fg * 32 + j) * H + o];
    const float bias = b[o];

    const int nbatch = (N + L1_ROWS - 1) / L1_ROWS;
    for (int batch = blockIdx.x; batch < nbatch; batch += gridDim.x) {
        const int row0 = batch * L1_ROWS;
#pragma unroll
        for (int bq = 0; bq < 4; ++bq) {
            int L  = bq * 256 + t;
            int rl = L >> 7;
            int f4 = L & 127;
            int r  = row0 + rl;
            float4 v = make_float4(0.f, 0.f, 0.f, 0.f);
            if (r < N) v = *(const float4*)&x[(size_t)r * F_IN + f4 * 4];
            int fgs = f4 >> 3, j4 = f4 & 7;
            *(float4*)&xs[rl][fgs * XS_CH + j4 * 4] = v;
        }
        __syncthreads();

        float acc[L1_ROWS];
#pragma unroll
        for (int r = 0; r < L1_ROWS; ++r) acc[r] = 0.f;
#pragma unroll
        for (int j4 = 0; j4 < 8; ++j4) {
#pragma unroll
            for (int r = 0; r < L1_ROWS; ++r) {
                float4 xv = *(const float4*)&xs[r][fg * XS_CH + j4 * 4];
                acc[r] = fmaf(xv.x, Wreg[j4 * 4 + 0], acc[r]);
                acc[r] = fmaf(xv.y, Wreg[j4 * 4 + 1], acc[r]);
                acc[r] = fmaf(xv.z, Wreg[j4 * 4 + 2], acc[r]);
                acc[r] = fmaf(xv.w, Wreg[j4 * 4 + 3], acc[r]);
            }
        }
#pragma unroll
        for (int r = 0; r < L1_ROWS; ++r) part[r][fg * 16 + o] = acc[r];
        __syncthreads();

        if (t < 128) {
            int r = t >> 4, oo = t & 15;
            float s = 0.f;
#pragma unroll
            for (int g = 0; g < 16; ++g) s += part[r][g * 16 + oo];
            s = fmaxf(s + bias, 0.f);
            int rr = row0 + r;
            if (rr < N) h0[(size_t)rr * H + oo] = s;
        }
        __syncthreads();
    }
}

// ---------------- conv: hWs = dinv[n] * (h_in @ W) ----------------

__global__ __launch_bounds__(256) void mm16_kernel(const float* __restrict__ hin,
                                                   const float* __restrict__ W,
                                                   const float* __restrict__ dinv,
                                                   float* __restrict__ hWs, int N) {
    __shared__ float Wl[H * H];
    if (threadIdx.x < H * H) Wl[threadIdx.x] = W[threadIdx.x];
    __syncthreads();
    int n = blockIdx.x * 256 + threadIdx.x;
    if (n >= N) return;
    float hv[H];
#pragma unroll
    for (int k4 = 0; k4 < 4; ++k4) {
        float4 v = *(const float4*)&hin[(size_t)n * H + k4 * 4];
        hv[k4 * 4 + 0] = v.x; hv[k4 * 4 + 1] = v.y;
        hv[k4 * 4 + 2] = v.z; hv[k4 * 4 + 3] = v.w;
    }
    float acc[H];
#pragma unroll
    for (int c = 0; c < H; ++c) acc[c] = 0.f;
#pragma unroll
    for (int k = 0; k < H; ++k) {
#pragma unroll
        for (int c = 0; c < H; ++c) acc[c] = fmaf(hv[k], Wl[k * H + c], acc[c]);
    }
    float di = dinv[n];
#pragma unroll
    for (int c4 = 0; c4 < 4; ++c4) {
        float4 a = make_float4(di * acc[c4 * 4], di * acc[c4 * 4 + 1],
                               di * acc[c4 * 4 + 2], di * acc[c4 * 4 + 3]);
        *(float4*)&hWs[(size_t)n * H + c4 * 4] = a;
    }
}

// ---------------- gather: out[n][f] = relu(dinv[n]*(hWs[n][f] + sum ew*hWs[row][f]) + b[f]) ----
// 16 threads per node; lane f reads hWs[row*16+f] -> 64B coalesced per edge.

__global__ __launch_bounds__(256) void gather_kernel(const int* __restrict__ rowptr,
                                                     const int2* __restrict__ packed,
                                                     const float* __restrict__ hWs,
                                                     const float* __restrict__ dinv,
                                                     const float* __restrict__ b,
                                                     float* __restrict__ out, int N) {
    int t = blockIdx.x * 256 + threadIdx.x;
    int n = t >> 4, f = t & 15;
    if (n >= N) return;
    int s = rowptr[n], e = rowptr[n + 1];
    float acc = hWs[(size_t)n * H + f];  // self-loop term
    int i = s;
    // unroll-2 to keep two gathers in flight
    for (; i + 2 <= e; i += 2) {
        int2 p0 = packed[i], p1 = packed[i + 1];
        float h0 = hWs[(size_t)p0.x * H + f];
        float h1 = hWs[(size_t)p1.x * H + f];
        acc = fmaf(__int_as_float(p0.y), h0, acc);
        acc = fmaf(__int_as_float(p1.y), h1, acc);
    }
    if (i < e) {
        int2 p = packed[i];
        acc = fmaf(__int_as_float(p.y), hWs[(size_t)p.x * H + f], acc);
    }
    out[(size_t)n * H + f] = fmaxf(fmaf(dinv[n], acc, b[f]), 0.f);
}

// ---------------- output layer: log_softmax(h @ W_out + b_out) ----------------

__global__ __launch_bounds__(256) void out_kernel(const float* __restrict__ h,
                                                  const float* __restrict__ W,
                                                  const float* __restrict__ b,
                                                  float* __restrict__ out, int N, int C) {
    extern __shared__ float sm[];
    float* Wl = sm;
    float* bl = sm + H * C;
    for (int i = threadIdx.x; i < H * C; i += 256) Wl[i] = W[i];
    if (threadIdx.x < C) bl[threadIdx.x] = b[threadIdx.x];
    __syncthreads();
    int n = blockIdx.x * 256 + threadIdx.x;
    if (n >= N) return;
    float hv[H];
#pragma unroll
    for (int k4 = 0; k4 < 4; ++k4) {
        float4 v = *(const float4*)&h[(size_t)n * H + k4 * 4];
        hv[k4 * 4 + 0] = v.x; hv[k4 * 4 + 1] = v.y;
        hv[k4 * 4 + 2] = v.z; hv[k4 * 4 + 3] = v.w;
    }
    float acc[40];
    for (int c = 0; c < C; ++c) acc[c] = bl[c];
    for (int k = 0; k < H; ++k) {
        float xk = hv[k];
        for (int c = 0; c < C; ++c) acc[c] = fmaf(xk, Wl[k * C + c], acc[c]);
    }
    float m = -1e30f;
    for (int c = 0; c < C; ++c) m = fmaxf(m, acc[c]);
    float s = 0.f;
    for (int c = 0; c < C; ++c) s += __expf(acc[c] - m);
    float lse = m + __logf(s);
    for (int c = 0; c < C; ++c) acc[c] -= lse;
    for (int c4 = 0; c4 < C / 4; ++c4) {
        float4 v = make_float4(acc[c4 * 4], acc[c4 * 4 + 1], acc[c4 * 4 + 2], acc[c4 * 4 + 3]);
        *(float4*)&out[(size_t)n * C + c4 * 4] = v;
    }
}

// ---------------- launch ----------------

extern "C" void kernel_launch(void* const* d_in, const int* in_sizes, int n_in,
                              void* d_out, int out_size, void* d_ws, size_t ws_size,
                              hipStream_t stream) {
    const float* x       = (const float*)d_in[0];
    const int*   ei      = (const int*)d_in[1];
    const float* ew      = (const float*)d_in[2];
    const float* W_first = (const float*)d_in[3];
    const float* b_first = (const float*)d_in[4];
    const float* W_c1    = (const float*)d_in[5];
    const float* b_c1    = (const float*)d_in[6];
    const float* W_c2    = (const float*)d_in[7];
    const float* b_c2    = (const float*)d_in[8];
    const float* W_o     = (const float*)d_in[9];
    const float* b_o     = (const float*)d_in[10];

    const int N = in_sizes[0] / F_IN;
    const int E = in_sizes[2];
    const int C = in_sizes[10];
    const int NBLK = (N + 255) / 256;

    const int* row = ei;      // edge_index[0] = source
    const int* col = ei + E;  // edge_index[1] = target

    char* wsb = (char*)d_ws;
    int*   cnt    = (int*)wsb;                     wsb += (size_t)N * 4;
    int*   fill   = (int*)wsb;                     wsb += (size_t)N * 4;
    int*   rowptr = (int*)wsb;                     wsb += (size_t)(N + 1) * 4;
    int*   bsum   = (int*)wsb;                     wsb += (size_t)NBLK * 4 + 4;
    float* dinv   = (float*)wsb;                   wsb += (size_t)N * 4;
    int2*  packed = (int2*)wsb;                    wsb += (size_t)E * 8;
    float* bufA   = (float*)wsb;                   wsb += (size_t)N * H * 4;
    float* bufB   = (float*)wsb;                   wsb += (size_t)N * H * 4;

    // zero cnt + fill (adjacent)
    hipMemsetAsync(cnt, 0, (size_t)N * 2 * 4, stream);

    // CSR build (shared by both convs)
    cnt_kernel<<<(E + 255) / 256, 256, 0, stream>>>(col, cnt, E);
    bsum_kernel<<<NBLK, 256, 0, stream>>>(cnt, bsum, N);
    scan_bsum_kernel<<<1, 512, 0, stream>>>(bsum, NBLK);
    rowptr_kernel<<<NBLK, 256, 0, stream>>>(cnt, bsum, rowptr, N, E);
    place_kernel<<<(E + 255) / 256, 256, 0, stream>>>(row, col, ew, rowptr, fill, packed, E);
    segdeg_kernel<<<NBLK, 256, 0, stream>>>(rowptr, packed, dinv, N);

    // layer 1
    l1_kernel<<<1024, 256, 0, stream>>>(x, W_first, b_first, bufA, N);

    // conv1
    mm16_kernel<<<NBLK, 256, 0, stream>>>(bufA, W_c1, dinv, bufB, N);
    gather_kernel<<<(N * 16 + 255) / 256, 256, 0, stream>>>(rowptr, packed, bufB, dinv, b_c1, bufA, N);

    // conv2
    mm16_kernel<<<NBLK, 256, 0, stream>>>(bufA, W_c2, dinv, bufB, N);
    gather_kernel<<<(N * 16 + 255) / 256, 256, 0, stream>>>(rowptr, packed, bufB, dinv, b_c2, bufA, N);

    // output + log_softmax
    size_t smem = (size_t)(H * C + C) * sizeof(float);
    out_kernel<<<(N + 255) / 256, 256, smem, stream>>>(bufA, W_o, b_o, (float*)d_out, N, C);
}

// Round 3
// 758.491 us; speedup vs baseline: 2.5160x; 1.1348x over previous
//
#include <hip/hip_runtime.h>
#include <hip/hip_bf16.h>
#include <math.h>

// Problem constants: N=100000, E=3200000, F_IN=512, H=16, C=40
#define F_IN 512
#define H 16
#define BSH 7                 // bucket shift: 128 nodes per bucket
#define BNODES (1 << BSH)
#define EPT 16                // edges per thread in hist/bin
#define CAP 5376              // max edges per bucket staged in LDS (mean 4096, 20 sigma)

// ---------------- two-level counting sort: hist -> scan -> bin -> pass2 ----------------

__global__ __launch_bounds__(256) void hist_kernel(const int* __restrict__ col,
                                                   int* __restrict__ bcnt, int E, int NBUCK) {
    extern __shared__ int hs[];  // NBUCK ints
    const int t = threadIdx.x;
    for (int i = t; i < NBUCK; i += 256) hs[i] = 0;
    __syncthreads();
    int e0 = blockIdx.x * (256 * EPT) + t;
#pragma unroll
    for (int k = 0; k < EPT; ++k) {
        int e = e0 + k * 256;
        if (e < E) atomicAdd(&hs[col[e] >> BSH], 1);
    }
    __syncthreads();
    for (int i = t; i < NBUCK; i += 256) {
        int h = hs[i];
        if (h > 0) atomicAdd(&bcnt[i], h);
    }
}

// 1 block, 1024 threads: exclusive scan of NBUCK (<1024) bucket counts
__global__ void bscan_kernel(const int* __restrict__ bcnt, int* __restrict__ bbase,
                             int* __restrict__ rowptr, int NBUCK, int E, int N) {
    __shared__ int sm[1024];
    int t = threadIdx.x;
    int v = (t < NBUCK) ? bcnt[t] : 0;
    sm[t] = v;
    __syncthreads();
    for (int o = 1; o < 1024; o <<= 1) {
        int u = (t >= o) ? sm[t - o] : 0;
        __syncthreads();
        sm[t] += u;
        __syncthreads();
    }
    if (t < NBUCK) bbase[t] = sm[t] - v;
    if (t == 0) { bbase[NBUCK] = E; rowptr[N] = E; }
}

__global__ __launch_bounds__(256) void bin_kernel(const int* __restrict__ row,
                                                  const int* __restrict__ col,
                                                  const float* __restrict__ ew,
                                                  const int* __restrict__ bbase,
                                                  int* __restrict__ bfill,
                                                  int2* __restrict__ packed, int E, int NBUCK) {
    extern __shared__ int sh[];
    int* hs   = sh;           // NBUCK
    int* base = sh + NBUCK;   // NBUCK
    const int t = threadIdx.x;
    for (int i = t; i < NBUCK; i += 256) hs[i] = 0;
    __syncthreads();

    int  bk16[EPT], rk16[EPT], pa[EPT], pb[EPT];
    int e0 = blockIdx.x * (256 * EPT) + t;
#pragma unroll
    for (int k = 0; k < EPT; ++k) {
        int e = e0 + k * 256;
        if (e < E) {
            int c  = col[e];
            int bk = c >> BSH;
            bk16[k] = bk;
            rk16[k] = atomicAdd(&hs[bk], 1);
            pa[k]   = row[e] | ((c & (BNODES - 1)) << 17);
            pb[k]   = __float_as_int(ew[e]);
        } else bk16[k] = -1;
    }
    __syncthreads();
    // reserve a contiguous chunk per (block, bucket)
    for (int i = t; i < NBUCK; i += 256) {
        int h = hs[i];
        base[i] = (h > 0) ? atomicAdd(&bfill[i], h) : 0;
    }
    __syncthreads();
#pragma unroll
    for (int k = 0; k < EPT; ++k) {
        int bk = bk16[k];
        if (bk >= 0) {
            int dst = bbase[bk] + base[bk] + rk16[k];
            packed[dst] = make_int2(pa[k], pb[k]);
        }
    }
}

// One block per bucket: stage edges in LDS, per-node count/scan, rewrite bucket
// in place fully sorted; emit rowptr and dinv for the bucket's nodes.
__global__ __launch_bounds__(256) void pass2_kernel(const int* __restrict__ bbase,
                                                    int2* __restrict__ packed,
                                                    int* __restrict__ rowptr,
                                                    float* __restrict__ dinv, int N) {
    __shared__ int2  edg[CAP];
    __shared__ int   ncnt[BNODES], nsc[BNODES], nfill[BNODES];
    __shared__ float dsum[BNODES];
    const int t = threadIdx.x;
    const int b = blockIdx.x;
    const int s = bbase[b];
    int cnt = bbase[b + 1] - s;
    if (cnt > CAP) cnt = CAP;  // statistically impossible; clamp for safety

    for (int i = t; i < cnt; i += 256) edg[i] = packed[s + i];
    if (t < BNODES) { ncnt[t] = 0; nfill[t] = 0; dsum[t] = 0.f; }
    __syncthreads();

    for (int i = t; i < cnt; i += 256) {
        int lc = (edg[i].x >> 17) & (BNODES - 1);
        atomicAdd(&ncnt[lc], 1);
        atomicAdd(&dsum[lc], __int_as_float(edg[i].y));
    }
    __syncthreads();
    if (t < BNODES) nsc[t] = ncnt[t];
    __syncthreads();
    for (int o = 1; o < BNODES; o <<= 1) {
        int v = (t < BNODES && t >= o) ? nsc[t - o] : 0;
        __syncthreads();
        if (t < BNODES) nsc[t] += v;
        __syncthreads();
    }
    // nsc is inclusive; exclusive = nsc - ncnt
    if (t < BNODES) {
        int n = b * BNODES + t;
        if (n < N) {
            rowptr[n] = s + nsc[t] - ncnt[t];
            dinv[n]   = rsqrtf(1.0f + dsum[t]);   // self-loop weight 1
        }
    }
    __syncthreads();
    for (int i = t; i < cnt; i += 256) {
        int lc = (edg[i].x >> 17) & (BNODES - 1);
        int rk = atomicAdd(&nfill[lc], 1);
        packed[s + nsc[lc] - ncnt[lc] + rk] = make_int2(edg[i].x & 0x1FFFF, edg[i].y);
    }
}

// ---------------- layer 1: h0 = relu(x @ W_first + b_first) ----------------

#define L1_ROWS 8
#define XS_CH 36
#define XS_ROW (16 * XS_CH)

__global__ __launch_bounds__(256) void l1_kernel(const float* __restrict__ x,
                                                 const float* __restrict__ W,
                                                 const float* __restrict__ b,
                                                 float* __restrict__ h0, int N) {
    __shared__ float xs[L1_ROWS][XS_ROW];
    __shared__ float part[L1_ROWS][256];
    const int t  = threadIdx.x;
    const int o  = t & 15;
    const int fg = t >> 4;

    float Wreg[32];
#pragma unroll
    for (int j = 0; j < 32; ++j) Wreg[j] = W[(fg * 32 + j) * H + o];
    const float bias = b[o];

    const int nbatch = (N + L1_ROWS - 1) / L1_ROWS;
    for (int batch = blockIdx.x; batch < nbatch; batch += gridDim.x) {
        const int row0 = batch * L1_ROWS;
#pragma unroll
        for (int bq = 0; bq < 4; ++bq) {
            int L  = bq * 256 + t;
            int rl = L >> 7;
            int f4 = L & 127;
            int r  = row0 + rl;
            float4 v = make_float4(0.f, 0.f, 0.f, 0.f);
            if (r < N) v = *(const float4*)&x[(size_t)r * F_IN + f4 * 4];
            int fgs = f4 >> 3, j4 = f4 & 7;
            *(float4*)&xs[rl][fgs * XS_CH + j4 * 4] = v;
        }
        __syncthreads();

        float acc[L1_ROWS];
#pragma unroll
        for (int r = 0; r < L1_ROWS; ++r) acc[r] = 0.f;
#pragma unroll
        for (int j4 = 0; j4 < 8; ++j4) {
#pragma unroll
            for (int r = 0; r < L1_ROWS; ++r) {
                float4 xv = *(const float4*)&xs[r][fg * XS_CH + j4 * 4];
                acc[r] = fmaf(xv.x, Wreg[j4 * 4 + 0], acc[r]);
                acc[r] = fmaf(xv.y, Wreg[j4 * 4 + 1], acc[r]);
                acc[r] = fmaf(xv.z, Wreg[j4 * 4 + 2], acc[r]);
                acc[r] = fmaf(xv.w, Wreg[j4 * 4 + 3], acc[r]);
            }
        }
#pragma unroll
        for (int r = 0; r < L1_ROWS; ++r) part[r][fg * 16 + o] = acc[r];
        __syncthreads();

        if (t < 128) {
            int r = t >> 4, oo = t & 15;
            float s = 0.f;
#pragma unroll
            for (int g = 0; g < 16; ++g) s += part[r][g * 16 + oo];
            s = fmaxf(s + bias, 0.f);
            int rr = row0 + r;
            if (rr < N) h0[(size_t)rr * H + oo] = s;
        }
        __syncthreads();
    }
}

// ---------------- conv: hWs = dinv[n] * (h_in @ W) ----------------

__global__ __launch_bounds__(256) void mm16_kernel(const float* __restrict__ hin,
                                                   const float* __restrict__ W,
                                                   const float* __restrict__ dinv,
                                                   float* __restrict__ hWs, int N) {
    __shared__ float Wl[H * H];
    if (threadIdx.x < H * H) Wl[threadIdx.x] = W[threadIdx.x];
    __syncthreads();
    int n = blockIdx.x * 256 + threadIdx.x;
    if (n >= N) return;
    float hv[H];
#pragma unroll
    for (int k4 = 0; k4 < 4; ++k4) {
        float4 v = *(const float4*)&hin[(size_t)n * H + k4 * 4];
        hv[k4 * 4 + 0] = v.x; hv[k4 * 4 + 1] = v.y;
        hv[k4 * 4 + 2] = v.z; hv[k4 * 4 + 3] = v.w;
    }
    float acc[H];
#pragma unroll
    for (int c = 0; c < H; ++c) acc[c] = 0.f;
#pragma unroll
    for (int k = 0; k < H; ++k) {
#pragma unroll
        for (int c = 0; c < H; ++c) acc[c] = fmaf(hv[k], Wl[k * H + c], acc[c]);
    }
    float di = dinv[n];
#pragma unroll
    for (int c4 = 0; c4 < 4; ++c4) {
        float4 a = make_float4(di * acc[c4 * 4], di * acc[c4 * 4 + 1],
                               di * acc[c4 * 4 + 2], di * acc[c4 * 4 + 3]);
        *(float4*)&hWs[(size_t)n * H + c4 * 4] = a;
    }
}

// ---------------- gather: out[n][f] = relu(dinv[n]*(hWs[n][f] + sum ew*hWs[row][f]) + b[f]) ----

__global__ __launch_bounds__(256) void gather_kernel(const int* __restrict__ rowptr,
                                                     const int2* __restrict__ packed,
                                                     const float* __restrict__ hWs,
                                                     const float* __restrict__ dinv,
                                                     const float* __restrict__ b,
                                                     float* __restrict__ out, int N) {
    int t = blockIdx.x * 256 + threadIdx.x;
    int n = t >> 4, f = t & 15;
    if (n >= N) return;
    int s = rowptr[n], e = rowptr[n + 1];
    float acc = hWs[(size_t)n * H + f];  // self-loop term
    int i = s;
    for (; i + 2 <= e; i += 2) {
        int2 p0 = packed[i], p1 = packed[i + 1];
        float h0 = hWs[(size_t)p0.x * H + f];
        float h1 = hWs[(size_t)p1.x * H + f];
        acc = fmaf(__int_as_float(p0.y), h0, acc);
        acc = fmaf(__int_as_float(p1.y), h1, acc);
    }
    if (i < e) {
        int2 p = packed[i];
        acc = fmaf(__int_as_float(p.y), hWs[(size_t)p.x * H + f], acc);
    }
    out[(size_t)n * H + f] = fmaxf(fmaf(dinv[n], acc, b[f]), 0.f);
}

// ---------------- output layer: log_softmax(h @ W_out + b_out) ----------------

__global__ __launch_bounds__(256) void out_kernel(const float* __restrict__ h,
                                                  const float* __restrict__ W,
                                                  const float* __restrict__ b,
                                                  float* __restrict__ out, int N, int C) {
    extern __shared__ float sm[];
    float* Wl = sm;
    float* bl = sm + H * C;
    for (int i = threadIdx.x; i < H * C; i += 256) Wl[i] = W[i];
    if (threadIdx.x < C) bl[threadIdx.x] = b[threadIdx.x];
    __syncthreads();
    int n = blockIdx.x * 256 + threadIdx.x;
    if (n >= N) return;
    float hv[H];
#pragma unroll
    for (int k4 = 0; k4 < 4; ++k4) {
        float4 v = *(const float4*)&h[(size_t)n * H + k4 * 4];
        hv[k4 * 4 + 0] = v.x; hv[k4 * 4 + 1] = v.y;
        hv[k4 * 4 + 2] = v.z; hv[k4 * 4 + 3] = v.w;
    }
    float acc[40];
    for (int c = 0; c < C; ++c) acc[c] = bl[c];
    for (int k = 0; k < H; ++k) {
        float xk = hv[k];
        for (int c = 0; c < C; ++c) acc[c] = fmaf(xk, Wl[k * C + c], acc[c]);
    }
    float m = -1e30f;
    for (int c = 0; c < C; ++c) m = fmaxf(m, acc[c]);
    float s = 0.f;
    for (int c = 0; c < C; ++c) s += __expf(acc[c] - m);
    float lse = m + __logf(s);
    for (int c = 0; c < C; ++c) acc[c] -= lse;
    for (int c4 = 0; c4 < C / 4; ++c4) {
        float4 v = make_float4(acc[c4 * 4], acc[c4 * 4 + 1], acc[c4 * 4 + 2], acc[c4 * 4 + 3]);
        *(float4*)&out[(size_t)n * C + c4 * 4] = v;
    }
}

// ---------------- launch ----------------

extern "C" void kernel_launch(void* const* d_in, const int* in_sizes, int n_in,
                              void* d_out, int out_size, void* d_ws, size_t ws_size,
                              hipStream_t stream) {
    const float* x       = (const float*)d_in[0];
    const int*   ei      = (const int*)d_in[1];
    const float* ew      = (const float*)d_in[2];
    const float* W_first = (const float*)d_in[3];
    const float* b_first = (const float*)d_in[4];
    const float* W_c1    = (const float*)d_in[5];
    const float* b_c1    = (const float*)d_in[6];
    const float* W_c2    = (const float*)d_in[7];
    const float* b_c2    = (const float*)d_in[8];
    const float* W_o     = (const float*)d_in[9];
    const float* b_o     = (const float*)d_in[10];

    const int N = in_sizes[0] / F_IN;
    const int E = in_sizes[2];
    const int C = in_sizes[10];
    const int NBUCK = (N + BNODES - 1) >> BSH;          // 782
    const int HB    = (E + 256 * EPT - 1) / (256 * EPT); // 782

    const int* row = ei;      // edge_index[0] = source
    const int* col = ei + E;  // edge_index[1] = target

    char* wsb = (char*)d_ws;
    int*   bcnt   = (int*)wsb;                  wsb += (size_t)NBUCK * 4;
    int*   bfill  = (int*)wsb;                  wsb += (size_t)NBUCK * 4;
    int*   bbase  = (int*)wsb;                  wsb += (size_t)(NBUCK + 1) * 4;
    int*   rowptr = (int*)wsb;                  wsb += (size_t)(N + 1) * 4;
    float* dinv   = (float*)wsb;                wsb += (size_t)N * 4;
    int2*  packed = (int2*)wsb;                 wsb += (size_t)E * 8;
    float* bufA   = (float*)wsb;                wsb += (size_t)N * H * 4;
    float* bufB   = (float*)d_out;  // N*H floats; dead before out_kernel writes d_out

    // zero bucket counters (bcnt + bfill adjacent)
    hipMemsetAsync(bcnt, 0, (size_t)NBUCK * 2 * 4, stream);

    // CSR build via two-level counting sort (shared by both convs)
    hist_kernel<<<HB, 256, NBUCK * 4, stream>>>(col, bcnt, E, NBUCK);
    bscan_kernel<<<1, 1024, 0, stream>>>(bcnt, bbase, rowptr, NBUCK, E, N);
    bin_kernel<<<HB, 256, NBUCK * 8, stream>>>(row, col, ew, bbase, bfill, packed, E, NBUCK);
    pass2_kernel<<<NBUCK, 256, 0, stream>>>(bbase, packed, rowptr, dinv, N);

    // layer 1
    l1_kernel<<<1024, 256, 0, stream>>>(x, W_first, b_first, bufA, N);

    // conv1
    mm16_kernel<<<(N + 255) / 256, 256, 0, stream>>>(bufA, W_c1, dinv, bufB, N);
    gather_kernel<<<(N * 16 + 255) / 256, 256, 0, stream>>>(rowptr, packed, bufB, dinv, b_c1, bufA, N);

    // conv2
    mm16_kernel<<<(N + 255) / 256, 256, 0, stream>>>(bufA, W_c2, dinv, bufB, N);
    gather_kernel<<<(N * 16 + 255) / 256, 256, 0, stream>>>(rowptr, packed, bufB, dinv, b_c2, bufA, N);

    // output + log_softmax
    size_t smem = (size_t)(H * C + C) * sizeof(float);
    out_kernel<<<(N + 255) / 256, 256, smem, stream>>>(bufA, W_o, b_o, (float*)d_out, N, C);
}

// Round 4
// 749.265 us; speedup vs baseline: 2.5470x; 1.0123x over previous
//
#include <hip/hip_runtime.h>
#include <hip/hip_bf16.h>
#include <math.h>

// Problem constants: N=100000, E=3200000, F_IN=512, H=16, C=40
#define F_IN 512
#define H 16
#define BSH 7                 // bucket shift: 128 nodes per bucket
#define BNODES (1 << BSH)
#define EPT 64                // edges per thread in hist/bin (16384 edges per block)
#define CAP 5376              // max edges per bucket staged in LDS (mean 4096, 20 sigma)

// ---------------- two-level counting sort: hist -> scan -> bin -> pass2 ----------------

__global__ __launch_bounds__(256) void hist_kernel(const int* __restrict__ col,
                                                   int* __restrict__ bcnt, int E, int NBUCK) {
    extern __shared__ int hs[];  // NBUCK ints
    const int t = threadIdx.x;
    for (int i = t; i < NBUCK; i += 256) hs[i] = 0;
    __syncthreads();
    long long e0 = (long long)blockIdx.x * (256 * EPT) + t;
#pragma unroll 4
    for (int k = 0; k < EPT; ++k) {
        long long e = e0 + (long long)k * 256;
        if (e < E) atomicAdd(&hs[col[e] >> BSH], 1);
    }
    __syncthreads();
    for (int i = t; i < NBUCK; i += 256) {
        int h = hs[i];
        if (h > 0) atomicAdd(&bcnt[i], h);
    }
}

// 1 block, 1024 threads: exclusive scan of NBUCK (<1024) bucket counts
__global__ void bscan_kernel(const int* __restrict__ bcnt, int* __restrict__ bbase,
                             int* __restrict__ rowptr, int NBUCK, int E, int N) {
    __shared__ int sm[1024];
    int t = threadIdx.x;
    int v = (t < NBUCK) ? bcnt[t] : 0;
    sm[t] = v;
    __syncthreads();
    for (int o = 1; o < 1024; o <<= 1) {
        int u = (t >= o) ? sm[t - o] : 0;
        __syncthreads();
        sm[t] += u;
        __syncthreads();
    }
    if (t < NBUCK) bbase[t] = sm[t] - v;
    if (t == 0) { bbase[NBUCK] = E; rowptr[N] = E; }
}

// Two-phase: (A) count buckets in LDS, (B) reserve one global chunk per
// (block,bucket), (C) re-read edges and place via LDS fill counters.
__global__ __launch_bounds__(256) void bin_kernel(const int* __restrict__ row,
                                                  const int* __restrict__ col,
                                                  const float* __restrict__ ew,
                                                  const int* __restrict__ bbase,
                                                  int* __restrict__ bfill,
                                                  int2* __restrict__ packed, int E, int NBUCK) {
    extern __shared__ int sh[];
    int* hs   = sh;           // NBUCK: counts, then fill
    int* base = sh + NBUCK;   // NBUCK: global chunk base for this block
    const int t = threadIdx.x;
    for (int i = t; i < NBUCK; i += 256) hs[i] = 0;
    __syncthreads();

    const long long e0 = (long long)blockIdx.x * (256 * EPT) + t;
    // phase A: count
#pragma unroll 4
    for (int k = 0; k < EPT; ++k) {
        long long e = e0 + (long long)k * 256;
        if (e < E) atomicAdd(&hs[col[e] >> BSH], 1);
    }
    __syncthreads();
    // phase B: reserve a contiguous chunk per (block, bucket)
    for (int i = t; i < NBUCK; i += 256) {
        int h = hs[i];
        base[i] = (h > 0) ? atomicAdd(&bfill[i], h) : 0;
    }
    __syncthreads();
    for (int i = t; i < NBUCK; i += 256) hs[i] = 0;
    __syncthreads();
    // phase C: place
#pragma unroll 2
    for (int k = 0; k < EPT; ++k) {
        long long e = e0 + (long long)k * 256;
        if (e < E) {
            int c  = col[e];
            int bk = c >> BSH;
            int rk = atomicAdd(&hs[bk], 1);
            int dst = bbase[bk] + base[bk] + rk;
            packed[dst] = make_int2(row[e] | ((c & (BNODES - 1)) << 17),
                                    __float_as_int(ew[e]));
        }
    }
}

// One block per bucket: stage edges in LDS, per-node count/scan, rewrite bucket
// in place fully sorted; emit rowptr and dinv for the bucket's nodes.
__global__ __launch_bounds__(256) void pass2_kernel(const int* __restrict__ bbase,
                                                    int2* __restrict__ packed,
                                                    int* __restrict__ rowptr,
                                                    float* __restrict__ dinv, int N) {
    __shared__ int2  edg[CAP];
    __shared__ int   ncnt[BNODES], nsc[BNODES], nfill[BNODES];
    __shared__ float dsum[BNODES];
    const int t = threadIdx.x;
    const int b = blockIdx.x;
    const int s = bbase[b];
    int cnt = bbase[b + 1] - s;
    if (cnt > CAP) cnt = CAP;  // statistically impossible; clamp for safety

    for (int i = t; i < cnt; i += 256) edg[i] = packed[s + i];
    if (t < BNODES) { ncnt[t] = 0; nfill[t] = 0; dsum[t] = 0.f; }
    __syncthreads();

    for (int i = t; i < cnt; i += 256) {
        int lc = (edg[i].x >> 17) & (BNODES - 1);
        atomicAdd(&ncnt[lc], 1);
        atomicAdd(&dsum[lc], __int_as_float(edg[i].y));
    }
    __syncthreads();
    if (t < BNODES) nsc[t] = ncnt[t];
    __syncthreads();
    for (int o = 1; o < BNODES; o <<= 1) {
        int v = (t < BNODES && t >= o) ? nsc[t - o] : 0;
        __syncthreads();
        if (t < BNODES) nsc[t] += v;
        __syncthreads();
    }
    // nsc is inclusive; exclusive = nsc - ncnt
    if (t < BNODES) {
        int n = b * BNODES + t;
        if (n < N) {
            rowptr[n] = s + nsc[t] - ncnt[t];
            dinv[n]   = rsqrtf(1.0f + dsum[t]);   // self-loop weight 1
        }
    }
    __syncthreads();
    for (int i = t; i < cnt; i += 256) {
        int lc = (edg[i].x >> 17) & (BNODES - 1);
        int rk = atomicAdd(&nfill[lc], 1);
        packed[s + nsc[lc] - ncnt[lc] + rk] = make_int2(edg[i].x & 0x1FFFF, edg[i].y);
    }
}

// ---------------- layer 1: h0 = relu(x @ W_first + b_first) ----------------

#define L1_ROWS 8
#define XS_CH 36
#define XS_ROW (16 * XS_CH)

__global__ __launch_bounds__(256) void l1_kernel(const float* __restrict__ x,
                                                 const float* __restrict__ W,
                                                 const float* __restrict__ b,
                                                 float* __restrict__ h0, int N) {
    __shared__ float xs[L1_ROWS][XS_ROW];
    __shared__ float part[L1_ROWS][256];
    const int t  = threadIdx.x;
    const int o  = t & 15;
    const int fg = t >> 4;

    float Wreg[32];
#pragma unroll
    for (int j = 0; j < 32; ++j) Wreg[j] = W[(fg * 32 + j) * H + o];
    const float bias = b[o];

    const int nbatch = (N + L1_ROWS - 1) / L1_ROWS;
    for (int batch = blockIdx.x; batch < nbatch; batch += gridDim.x) {
        const int row0 = batch * L1_ROWS;
#pragma unroll
        for (int bq = 0; bq < 4; ++bq) {
            int L  = bq * 256 + t;
            int rl = L >> 7;
            int f4 = L & 127;
            int r  = row0 + rl;
            float4 v = make_float4(0.f, 0.f, 0.f, 0.f);
            if (r < N) v = *(const float4*)&x[(size_t)r * F_IN + f4 * 4];
            int fgs = f4 >> 3, j4 = f4 & 7;
            *(float4*)&xs[rl][fgs * XS_CH + j4 * 4] = v;
        }
        __syncthreads();

        float acc[L1_ROWS];
#pragma unroll
        for (int r = 0; r < L1_ROWS; ++r) acc[r] = 0.f;
#pragma unroll
        for (int j4 = 0; j4 < 8; ++j4) {
#pragma unroll
            for (int r = 0; r < L1_ROWS; ++r) {
                float4 xv = *(const float4*)&xs[r][fg * XS_CH + j4 * 4];
                acc[r] = fmaf(xv.x, Wreg[j4 * 4 + 0], acc[r]);
                acc[r] = fmaf(xv.y, Wreg[j4 * 4 + 1], acc[r]);
                acc[r] = fmaf(xv.z, Wreg[j4 * 4 + 2], acc[r]);
                acc[r] = fmaf(xv.w, Wreg[j4 * 4 + 3], acc[r]);
            }
        }
#pragma unroll
        for (int r = 0; r < L1_ROWS; ++r) part[r][fg * 16 + o] = acc[r];
        __syncthreads();

        if (t < 128) {
            int r = t >> 4, oo = t & 15;
            float s = 0.f;
#pragma unroll
            for (int g = 0; g < 16; ++g) s += part[r][g * 16 + oo];
            s = fmaxf(s + bias, 0.f);
            int rr = row0 + r;
            if (rr < N) h0[(size_t)rr * H + oo] = s;
        }
        __syncthreads();
    }
}

// ---------------- conv: hWs = dinv[n] * (h_in @ W) ----------------

__global__ __launch_bounds__(256) void mm16_kernel(const float* __restrict__ hin,
                                                   const float* __restrict__ W,
                                                   const float* __restrict__ dinv,
                                                   float* __restrict__ hWs, int N) {
    __shared__ float Wl[H * H];
    if (threadIdx.x < H * H) Wl[threadIdx.x] = W[threadIdx.x];
    __syncthreads();
    int n = blockIdx.x * 256 + threadIdx.x;
    if (n >= N) return;
    float hv[H];
#pragma unroll
    for (int k4 = 0; k4 < 4; ++k4) {
        float4 v = *(const float4*)&hin[(size_t)n * H + k4 * 4];
        hv[k4 * 4 + 0] = v.x; hv[k4 * 4 + 1] = v.y;
        hv[k4 * 4 + 2] = v.z; hv[k4 * 4 + 3] = v.w;
    }
    float acc[H];
#pragma unroll
    for (int c = 0; c < H; ++c) acc[c] = 0.f;
#pragma unroll
    for (int k = 0; k < H; ++k) {
#pragma unroll
        for (int c = 0; c < H; ++c) acc[c] = fmaf(hv[k], Wl[k * H + c], acc[c]);
    }
    float di = dinv[n];
#pragma unroll
    for (int c4 = 0; c4 < 4; ++c4) {
        float4 a = make_float4(di * acc[c4 * 4], di * acc[c4 * 4 + 1],
                               di * acc[c4 * 4 + 2], di * acc[c4 * 4 + 3]);
        *(float4*)&hWs[(size_t)n * H + c4 * 4] = a;
    }
}

// ---------------- gather: out[n][f] = relu(dinv[n]*(hWs[n][f] + sum ew*hWs[row][f]) + b[f]) ----

__global__ __launch_bounds__(256) void gather_kernel(const int* __restrict__ rowptr,
                                                     const int2* __restrict__ packed,
                                                     const float* __restrict__ hWs,
                                                     const float* __restrict__ dinv,
                                                     const float* __restrict__ b,
                                                     float* __restrict__ out, int N) {
    int t = blockIdx.x * 256 + threadIdx.x;
    int n = t >> 4, f = t & 15;
    if (n >= N) return;
    int s = rowptr[n], e = rowptr[n + 1];
    float acc = hWs[(size_t)n * H + f];  // self-loop term
    int i = s;
    for (; i + 2 <= e; i += 2) {
        int2 p0 = packed[i], p1 = packed[i + 1];
        float h0 = hWs[(size_t)p0.x * H + f];
        float h1 = hWs[(size_t)p1.x * H + f];
        acc = fmaf(__int_as_float(p0.y), h0, acc);
        acc = fmaf(__int_as_float(p1.y), h1, acc);
    }
    if (i < e) {
        int2 p = packed[i];
        acc = fmaf(__int_as_float(p.y), hWs[(size_t)p.x * H + f], acc);
    }
    out[(size_t)n * H + f] = fmaxf(fmaf(dinv[n], acc, b[f]), 0.f);
}

// ---------------- output layer: log_softmax(h @ W_out + b_out) ----------------

__global__ __launch_bounds__(256) void out_kernel(const float* __restrict__ h,
                                                  const float* __restrict__ W,
                                                  const float* __restrict__ b,
                                                  float* __restrict__ out, int N, int C) {
    extern __shared__ float sm[];
    float* Wl = sm;
    float* bl = sm + H * C;
    for (int i = threadIdx.x; i < H * C; i += 256) Wl[i] = W[i];
    if (threadIdx.x < C) bl[threadIdx.x] = b[threadIdx.x];
    __syncthreads();
    int n = blockIdx.x * 256 + threadIdx.x;
    if (n >= N) return;
    float hv[H];
#pragma unroll
    for (int k4 = 0; k4 < 4; ++k4) {
        float4 v = *(const float4*)&h[(size_t)n * H + k4 * 4];
        hv[k4 * 4 + 0] = v.x; hv[k4 * 4 + 1] = v.y;
        hv[k4 * 4 + 2] = v.z; hv[k4 * 4 + 3] = v.w;
    }
    float acc[40];
    for (int c = 0; c < C; ++c) acc[c] = bl[c];
    for (int k = 0; k < H; ++k) {
        float xk = hv[k];
        for (int c = 0; c < C; ++c) acc[c] = fmaf(xk, Wl[k * C + c], acc[c]);
    }
    float m = -1e30f;
    for (int c = 0; c < C; ++c) m = fmaxf(m, acc[c]);
    float s = 0.f;
    for (int c = 0; c < C; ++c) s += __expf(acc[c] - m);
    float lse = m + __logf(s);
    for (int c = 0; c < C; ++c) acc[c] -= lse;
    for (int c4 = 0; c4 < C / 4; ++c4) {
        float4 v = make_float4(acc[c4 * 4], acc[c4 * 4 + 1], acc[c4 * 4 + 2], acc[c4 * 4 + 3]);
        *(float4*)&out[(size_t)n * C + c4 * 4] = v;
    }
}

// ---------------- launch ----------------

extern "C" void kernel_launch(void* const* d_in, const int* in_sizes, int n_in,
                              void* d_out, int out_size, void* d_ws, size_t ws_size,
                              hipStream_t stream) {
    const float* x       = (const float*)d_in[0];
    const int*   ei      = (const int*)d_in[1];
    const float* ew      = (const float*)d_in[2];
    const float* W_first = (const float*)d_in[3];
    const float* b_first = (const float*)d_in[4];
    const float* W_c1    = (const float*)d_in[5];
    const float* b_c1    = (const float*)d_in[6];
    const float* W_c2    = (const float*)d_in[7];
    const float* b_c2    = (const float*)d_in[8];
    const float* W_o     = (const float*)d_in[9];
    const float* b_o     = (const float*)d_in[10];

    const int N = in_sizes[0] / F_IN;
    const int E = in_sizes[2];
    const int C = in_sizes[10];
    const int NBUCK = (N + BNODES - 1) >> BSH;           // 782
    const int HB    = (E + 256 * EPT - 1) / (256 * EPT); // 196

    const int* row = ei;      // edge_index[0] = source
    const int* col = ei + E;  // edge_index[1] = target

    char* wsb = (char*)d_ws;
    int*   bcnt   = (int*)wsb;                  wsb += (size_t)NBUCK * 4;
    int*   bfill  = (int*)wsb;                  wsb += (size_t)NBUCK * 4;
    int*   bbase  = (int*)wsb;                  wsb += (size_t)(NBUCK + 1) * 4;
    int*   rowptr = (int*)wsb;                  wsb += (size_t)(N + 1) * 4;
    float* dinv   = (float*)wsb;                wsb += (size_t)N * 4;
    int2*  packed = (int2*)wsb;                 wsb += (size_t)E * 8;
    float* bufA   = (float*)wsb;                wsb += (size_t)N * H * 4;
    float* bufB   = (float*)d_out;  // N*H floats; dead before out_kernel writes d_out

    // zero bucket counters (bcnt + bfill adjacent)
    hipMemsetAsync(bcnt, 0, (size_t)NBUCK * 2 * 4, stream);

    // CSR build via two-level counting sort (shared by both convs)
    hist_kernel<<<HB, 256, NBUCK * 4, stream>>>(col, bcnt, E, NBUCK);
    bscan_kernel<<<1, 1024, 0, stream>>>(bcnt, bbase, rowptr, NBUCK, E, N);
    bin_kernel<<<HB, 256, NBUCK * 8, stream>>>(row, col, ew, bbase, bfill, packed, E, NBUCK);
    pass2_kernel<<<NBUCK, 256, 0, stream>>>(bbase, packed, rowptr, dinv, N);

    // layer 1
    l1_kernel<<<1024, 256, 0, stream>>>(x, W_first, b_first, bufA, N);

    // conv1
    mm16_kernel<<<(N + 255) / 256, 256, 0, stream>>>(bufA, W_c1, dinv, bufB, N);
    gather_kernel<<<(N * 16 + 255) / 256, 256, 0, stream>>>(rowptr, packed, bufB, dinv, b_c1, bufA, N);

    // conv2
    mm16_kernel<<<(N + 255) / 256, 256, 0, stream>>>(bufA, W_c2, dinv, bufB, N);
    gather_kernel<<<(N * 16 + 255) / 256, 256, 0, stream>>>(rowptr, packed, bufB, dinv, b_c2, bufA, N);

    // output + log_softmax
    size_t smem = (size_t)(H * C + C) * sizeof(float);
    out_kernel<<<(N + 255) / 256, 256, smem, stream>>>(bufA, W_o, b_o, (float*)d_out, N, C);
}

// Round 5
// 687.266 us; speedup vs baseline: 2.7767x; 1.0902x over previous
//
#include <hip/hip_runtime.h>
#include <hip/hip_bf16.h>
#include <math.h>

// Problem constants: N=100000, E=3200000, F_IN=512, H=16, C=40
#define F_IN 512
#define H 16
#define BSH 7                 // final bucket: 128 nodes
#define BNODES (1 << BSH)
#define SSH 12                // super bucket: 4096 nodes (32 final buckets)
#define EPT 64                // edges per thread in hist
#define CAP 5376              // max edges per final bucket in pass2 LDS
#define SEG 4096              // edges staged per scat block
#define SL 33                 // slices per super in scat2

// ---------------- hist: global histogram of 782 final buckets ----------------

__global__ __launch_bounds__(256) void hist_kernel(const int* __restrict__ col,
                                                   int* __restrict__ bcnt, int E, int NBUCK) {
    extern __shared__ int hs[];  // NBUCK ints
    const int t = threadIdx.x;
    for (int i = t; i < NBUCK; i += 256) hs[i] = 0;
    __syncthreads();
    long long e0 = (long long)blockIdx.x * (256 * EPT) + t;
#pragma unroll 4
    for (int k = 0; k < EPT; ++k) {
        long long e = e0 + (long long)k * 256;
        if (e < E) atomicAdd(&hs[col[e] >> BSH], 1);
    }
    __syncthreads();
    for (int i = t; i < NBUCK; i += 256) {
        int h = hs[i];
        if (h > 0) atomicAdd(&bcnt[i], h);
    }
}

// 1 block, 1024 threads: exclusive scan -> bbase[782], sbase[nsup+1], rowptr[N]=E
__global__ void bscan_kernel(const int* __restrict__ bcnt, int* __restrict__ bbase,
                             int* __restrict__ sbase, int* __restrict__ rowptr,
                             int NBUCK, int nsup, int E, int N) {
    __shared__ int sm[1024];
    int t = threadIdx.x;
    int v = (t < NBUCK) ? bcnt[t] : 0;
    sm[t] = v;
    __syncthreads();
    for (int o = 1; o < 1024; o <<= 1) {
        int u = (t >= o) ? sm[t - o] : 0;
        __syncthreads();
        sm[t] += u;
        __syncthreads();
    }
    if (t < NBUCK) bbase[t] = sm[t] - v;
    if (t == 0) { bbase[NBUCK] = E; rowptr[N] = E; }
    __syncthreads();
    if (t < nsup) {
        int bk = t << (SSH - BSH);
        sbase[t] = (bk < NBUCK) ? (sm[bk] - bcnt[bk]) : E;
    }
    if (t == nsup) sbase[nsup] = E;
}

// ---------------- scat1: edges -> 25 super buckets (LDS-staged) ----------------
// payload: x = row | (col & 4095) << 17  (29 bits), y = ew bits

__global__ __launch_bounds__(256) void scat1_kernel(const int* __restrict__ row,
                                                    const int* __restrict__ col,
                                                    const float* __restrict__ ew,
                                                    const int* __restrict__ sbase,
                                                    int* __restrict__ sfill,
                                                    int2* __restrict__ ptmp, int E, int nsup) {
    __shared__ int2 stg[SEG];          // 32 KB
    __shared__ unsigned char sup[SEG]; // 4 KB
    __shared__ int cnt[32], base[32];
    const int t = threadIdx.x;
    const int e0 = blockIdx.x * SEG;
    int m = E - e0; if (m > SEG) m = SEG;
    if (t < 32) cnt[t] = 0;
    __syncthreads();
    for (int i = t; i < m; i += 256) {
        int e = e0 + i;
        int c = col[e];
        int s = c >> SSH;
        sup[i] = (unsigned char)s;
        atomicAdd(&cnt[s], 1);
        stg[i] = make_int2(row[e] | ((c & ((1 << SSH) - 1)) << 17), __float_as_int(ew[e]));
    }
    __syncthreads();
    if (t < nsup) {
        int h = cnt[t];
        base[t] = h ? atomicAdd(&sfill[t], h) : 0;
        cnt[t] = 0;
    }
    __syncthreads();
    for (int i = t; i < m; i += 256) {
        int s = sup[i];
        int rk = atomicAdd(&cnt[s], 1);
        ptmp[sbase[s] + base[s] + rk] = stg[i];
    }
}

// ---------------- scat2: super bucket slices -> 32 final buckets each ----------------

__global__ __launch_bounds__(256) void scat2_kernel(const int* __restrict__ sbase,
                                                    const int* __restrict__ bbase,
                                                    int* __restrict__ ffill,
                                                    const int2* __restrict__ ptmp,
                                                    int2* __restrict__ packed, int NBUCK) {
    __shared__ int2 stg[SEG];   // 32 KB
    __shared__ int cnt[32], base[32];
    const int t = threadIdx.x;
    const int s  = blockIdx.x / SL;
    const int sl = blockIdx.x % SL;
    const int ss = sbase[s];
    const int len = sbase[s + 1] - ss;
    const int lo = ss + (int)((long long)len * sl / SL);
    const int hi = ss + (int)((long long)len * (sl + 1) / SL);
    int m = hi - lo; if (m > SEG) m = SEG;  // statistically impossible overflow clamp
    if (t < 32) cnt[t] = 0;
    __syncthreads();
    for (int i = t; i < m; i += 256) {
        int2 p = ptmp[lo + i];
        stg[i] = p;
        int bk5 = ((unsigned)p.x >> (17 + BSH)) & 31;  // (col&4095)>>7
        atomicAdd(&cnt[bk5], 1);
    }
    __syncthreads();
    if (t < 32) {
        int bk = (s << 5) + t;
        int h = cnt[t];
        base[t] = (h && bk < NBUCK) ? atomicAdd(&ffill[bk], h) : 0;
        cnt[t] = 0;
    }
    __syncthreads();
    for (int i = t; i < m; i += 256) {
        int2 p = stg[i];
        int bk5 = ((unsigned)p.x >> (17 + BSH)) & 31;
        int rk = atomicAdd(&cnt[bk5], 1);
        int bk = (s << 5) + bk5;
        // final payload: row (17b) | lcol (7b) << 17
        packed[bbase[bk] + base[bk5] + rk] = make_int2(p.x & 0xFFFFFF, p.y);
    }
}

// One block per final bucket: stage edges in LDS, per-node count/scan, rewrite
// bucket in place fully sorted; emit rowptr and dinv for the bucket's nodes.
__global__ __launch_bounds__(256) void pass2_kernel(const int* __restrict__ bbase,
                                                    int2* __restrict__ packed,
                                                    int* __restrict__ rowptr,
                                                    float* __restrict__ dinv, int N) {
    __shared__ int2  edg[CAP];
    __shared__ int   ncnt[BNODES], nsc[BNODES], nfill[BNODES];
    __shared__ float dsum[BNODES];
    const int t = threadIdx.x;
    const int b = blockIdx.x;
    const int s = bbase[b];
    int cnt = bbase[b + 1] - s;
    if (cnt > CAP) cnt = CAP;

    for (int i = t; i < cnt; i += 256) edg[i] = packed[s + i];
    if (t < BNODES) { ncnt[t] = 0; nfill[t] = 0; dsum[t] = 0.f; }
    __syncthreads();

    for (int i = t; i < cnt; i += 256) {
        int lc = (edg[i].x >> 17) & (BNODES - 1);
        atomicAdd(&ncnt[lc], 1);
        atomicAdd(&dsum[lc], __int_as_float(edg[i].y));
    }
    __syncthreads();
    if (t < BNODES) nsc[t] = ncnt[t];
    __syncthreads();
    for (int o = 1; o < BNODES; o <<= 1) {
        int v = (t < BNODES && t >= o) ? nsc[t - o] : 0;
        __syncthreads();
        if (t < BNODES) nsc[t] += v;
        __syncthreads();
    }
    if (t < BNODES) {
        int n = b * BNODES + t;
        if (n < N) {
            rowptr[n] = s + nsc[t] - ncnt[t];
            dinv[n]   = rsqrtf(1.0f + dsum[t]);   // self-loop weight 1
        }
    }
    __syncthreads();
    for (int i = t; i < cnt; i += 256) {
        int lc = (edg[i].x >> 17) & (BNODES - 1);
        int rk = atomicAdd(&nfill[lc], 1);
        packed[s + nsc[lc] - ncnt[lc] + rk] = make_int2(edg[i].x & 0x1FFFF, edg[i].y);
    }
}

// ---------------- layer 1: h0 = relu(x @ W_first + b_first) ----------------

#define L1_ROWS 8
#define XS_CH 36
#define XS_ROW (16 * XS_CH)

__global__ __launch_bounds__(256) void l1_kernel(const float* __restrict__ x,
                                                 const float* __restrict__ W,
                                                 const float* __restrict__ b,
                                                 float* __restrict__ h0, int N) {
    __shared__ float xs[L1_ROWS][XS_ROW];
    __shared__ float part[L1_ROWS][256];
    const int t  = threadIdx.x;
    const int o  = t & 15;
    const int fg = t >> 4;

    float Wreg[32];
#pragma unroll
    for (int j = 0; j < 32; ++j) Wreg[j] = W[(fg * 32 + j) * H + o];
    const float bias = b[o];

    const int nbatch = (N + L1_ROWS - 1) / L1_ROWS;
    for (int batch = blockIdx.x; batch < nbatch; batch += gridDim.x) {
        const int row0 = batch * L1_ROWS;
#pragma unroll
        for (int bq = 0; bq < 4; ++bq) {
            int L  = bq * 256 + t;
            int rl = L >> 7;
            int f4 = L & 127;
            int r  = row0 + rl;
            float4 v = make_float4(0.f, 0.f, 0.f, 0.f);
            if (r < N) v = *(const float4*)&x[(size_t)r * F_IN + f4 * 4];
            int fgs = f4 >> 3, j4 = f4 & 7;
            *(float4*)&xs[rl][fgs * XS_CH + j4 * 4] = v;
        }
        __syncthreads();

        float acc[L1_ROWS];
#pragma unroll
        for (int r = 0; r < L1_ROWS; ++r) acc[r] = 0.f;
#pragma unroll
        for (int j4 = 0; j4 < 8; ++j4) {
#pragma unroll
            for (int r = 0; r < L1_ROWS; ++r) {
                float4 xv = *(const float4*)&xs[r][fg * XS_CH + j4 * 4];
                acc[r] = fmaf(xv.x, Wreg[j4 * 4 + 0], acc[r]);
                acc[r] = fmaf(xv.y, Wreg[j4 * 4 + 1], acc[r]);
                acc[r] = fmaf(xv.z, Wreg[j4 * 4 + 2], acc[r]);
                acc[r] = fmaf(xv.w, Wreg[j4 * 4 + 3], acc[r]);
            }
        }
#pragma unroll
        for (int r = 0; r < L1_ROWS; ++r) part[r][fg * 16 + o] = acc[r];
        __syncthreads();

        if (t < 128) {
            int r = t >> 4, oo = t & 15;
            float s = 0.f;
#pragma unroll
            for (int g = 0; g < 16; ++g) s += part[r][g * 16 + oo];
            s = fmaxf(s + bias, 0.f);
            int rr = row0 + r;
            if (rr < N) h0[(size_t)rr * H + oo] = s;
        }
        __syncthreads();
    }
}

// ---------------- conv: hWs = dinv[n] * (h_in @ W) ----------------

__global__ __launch_bounds__(256) void mm16_kernel(const float* __restrict__ hin,
                                                   const float* __restrict__ W,
                                                   const float* __restrict__ dinv,
                                                   float* __restrict__ hWs, int N) {
    __shared__ float Wl[H * H];
    if (threadIdx.x < H * H) Wl[threadIdx.x] = W[threadIdx.x];
    __syncthreads();
    int n = blockIdx.x * 256 + threadIdx.x;
    if (n >= N) return;
    float hv[H];
#pragma unroll
    for (int k4 = 0; k4 < 4; ++k4) {
        float4 v = *(const float4*)&hin[(size_t)n * H + k4 * 4];
        hv[k4 * 4 + 0] = v.x; hv[k4 * 4 + 1] = v.y;
        hv[k4 * 4 + 2] = v.z; hv[k4 * 4 + 3] = v.w;
    }
    float acc[H];
#pragma unroll
    for (int c = 0; c < H; ++c) acc[c] = 0.f;
#pragma unroll
    for (int k = 0; k < H; ++k) {
#pragma unroll
        for (int c = 0; c < H; ++c) acc[c] = fmaf(hv[k], Wl[k * H + c], acc[c]);
    }
    float di = dinv[n];
#pragma unroll
    for (int c4 = 0; c4 < 4; ++c4) {
        float4 a = make_float4(di * acc[c4 * 4], di * acc[c4 * 4 + 1],
                               di * acc[c4 * 4 + 2], di * acc[c4 * 4 + 3]);
        *(float4*)&hWs[(size_t)n * H + c4 * 4] = a;
    }
}

// ---------------- gather: out[n][f] = relu(dinv[n]*(hWs[n][f] + sum ew*hWs[row][f]) + b[f]) ----

__global__ __launch_bounds__(256) void gather_kernel(const int* __restrict__ rowptr,
                                                     const int2* __restrict__ packed,
                                                     const float* __restrict__ hWs,
                                                     const float* __restrict__ dinv,
                                                     const float* __restrict__ b,
                                                     float* __restrict__ out, int N) {
    int t = blockIdx.x * 256 + threadIdx.x;
    int n = t >> 4, f = t & 15;
    if (n >= N) return;
    int s = rowptr[n], e = rowptr[n + 1];
    float acc = hWs[(size_t)n * H + f];  // self-loop term
    int i = s;
    for (; i + 2 <= e; i += 2) {
        int2 p0 = packed[i], p1 = packed[i + 1];
        float h0 = hWs[(size_t)p0.x * H + f];
        float h1 = hWs[(size_t)p1.x * H + f];
        acc = fmaf(__int_as_float(p0.y), h0, acc);
        acc = fmaf(__int_as_float(p1.y), h1, acc);
    }
    if (i < e) {
        int2 p = packed[i];
        acc = fmaf(__int_as_float(p.y), hWs[(size_t)p.x * H + f], acc);
    }
    out[(size_t)n * H + f] = fmaxf(fmaf(dinv[n], acc, b[f]), 0.f);
}

// ---------------- output layer: log_softmax(h @ W_out + b_out) ----------------

__global__ __launch_bounds__(256) void out_kernel(const float* __restrict__ h,
                                                  const float* __restrict__ W,
                                                  const float* __restrict__ b,
                                                  float* __restrict__ out, int N, int C) {
    extern __shared__ float sm[];
    float* Wl = sm;
    float* bl = sm + H * C;
    for (int i = threadIdx.x; i < H * C; i += 256) Wl[i] = W[i];
    if (threadIdx.x < C) bl[threadIdx.x] = b[threadIdx.x];
    __syncthreads();
    int n = blockIdx.x * 256 + threadIdx.x;
    if (n >= N) return;
    float hv[H];
#pragma unroll
    for (int k4 = 0; k4 < 4; ++k4) {
        float4 v = *(const float4*)&h[(size_t)n * H + k4 * 4];
        hv[k4 * 4 + 0] = v.x; hv[k4 * 4 + 1] = v.y;
        hv[k4 * 4 + 2] = v.z; hv[k4 * 4 + 3] = v.w;
    }
    float acc[40];
    for (int c = 0; c < C; ++c) acc[c] = bl[c];
    for (int k = 0; k < H; ++k) {
        float xk = hv[k];
        for (int c = 0; c < C; ++c) acc[c] = fmaf(xk, Wl[k * C + c], acc[c]);
    }
    float m = -1e30f;
    for (int c = 0; c < C; ++c) m = fmaxf(m, acc[c]);
    float s = 0.f;
    for (int c = 0; c < C; ++c) s += __expf(acc[c] - m);
    float lse = m + __logf(s);
    for (int c = 0; c < C; ++c) acc[c] -= lse;
    for (int c4 = 0; c4 < C / 4; ++c4) {
        float4 v = make_float4(acc[c4 * 4], acc[c4 * 4 + 1], acc[c4 * 4 + 2], acc[c4 * 4 + 3]);
        *(float4*)&out[(size_t)n * C + c4 * 4] = v;
    }
}

// ---------------- launch ----------------

extern "C" void kernel_launch(void* const* d_in, const int* in_sizes, int n_in,
                              void* d_out, int out_size, void* d_ws, size_t ws_size,
                              hipStream_t stream) {
    const float* x       = (const float*)d_in[0];
    const int*   ei      = (const int*)d_in[1];
    const float* ew      = (const float*)d_in[2];
    const float* W_first = (const float*)d_in[3];
    const float* b_first = (const float*)d_in[4];
    const float* W_c1    = (const float*)d_in[5];
    const float* b_c1    = (const float*)d_in[6];
    const float* W_c2    = (const float*)d_in[7];
    const float* b_c2    = (const float*)d_in[8];
    const float* W_o     = (const float*)d_in[9];
    const float* b_o     = (const float*)d_in[10];

    const int N = in_sizes[0] / F_IN;
    const int E = in_sizes[2];
    const int C = in_sizes[10];
    const int NBUCK = (N + BNODES - 1) >> BSH;            // 782
    const int NSUP  = ((N - 1) >> SSH) + 1;               // 25
    const int HB    = (E + 256 * EPT - 1) / (256 * EPT);  // 196
    const int SB    = (E + SEG - 1) / SEG;                // 782

    const int* row = ei;      // edge_index[0] = source
    const int* col = ei + E;  // edge_index[1] = target

    char* wsb = (char*)d_ws;
    int*   bcnt   = (int*)wsb;                  wsb += (size_t)NBUCK * 4;
    int*   sfill  = (int*)wsb;                  wsb += (size_t)32 * 4;
    int*   ffill  = (int*)wsb;                  wsb += (size_t)NBUCK * 4;
    int*   bbase  = (int*)wsb;                  wsb += (size_t)(NBUCK + 1) * 4;
    int*   sbase  = (int*)wsb;                  wsb += (size_t)(NSUP + 1) * 4;
    int*   rowptr = (int*)wsb;                  wsb += (size_t)(N + 1) * 4;
    float* dinv   = (float*)wsb;                wsb += (size_t)N * 4;
    int2*  packed = (int2*)wsb;                 wsb += (size_t)E * 8;
    int2*  ptmp   = (int2*)wsb;                 wsb += (size_t)E * 8;
    float* bufA   = (float*)ptmp;   // aliases ptmp (dead after scat2)
    float* bufB   = (float*)d_out;  // N*H floats; dead before out_kernel writes d_out

    // zero bcnt + sfill + ffill (contiguous)
    hipMemsetAsync(bcnt, 0, (size_t)(NBUCK * 2 + 32) * 4, stream);

    // CSR build: hist -> scan -> super scatter -> final scatter -> node sort
    hist_kernel<<<HB, 256, NBUCK * 4, stream>>>(col, bcnt, E, NBUCK);
    bscan_kernel<<<1, 1024, 0, stream>>>(bcnt, bbase, sbase, rowptr, NBUCK, NSUP, E, N);
    scat1_kernel<<<SB, 256, 0, stream>>>(row, col, ew, sbase, sfill, ptmp, E, NSUP);
    scat2_kernel<<<NSUP * SL, 256, 0, stream>>>(sbase, bbase, ffill, ptmp, packed, NBUCK);
    pass2_kernel<<<NBUCK, 256, 0, stream>>>(bbase, packed, rowptr, dinv, N);

    // layer 1
    l1_kernel<<<1024, 256, 0, stream>>>(x, W_first, b_first, bufA, N);

    // conv1
    mm16_kernel<<<(N + 255) / 256, 256, 0, stream>>>(bufA, W_c1, dinv, bufB, N);
    gather_kernel<<<(N * 16 + 255) / 256, 256, 0, stream>>>(rowptr, packed, bufB, dinv, b_c1, bufA, N);

    // conv2
    mm16_kernel<<<(N + 255) / 256, 256, 0, stream>>>(bufA, W_c2, dinv, bufB, N);
    gather_kernel<<<(N * 16 + 255) / 256, 256, 0, stream>>>(rowptr, packed, bufB, dinv, b_c2, bufA, N);

    // output + log_softmax
    size_t smem = (size_t)(H * C + C) * sizeof(float);
    out_kernel<<<(N + 255) / 256, 256, smem, stream>>>(bufA, W_o, b_o, (float*)d_out, N, C);
}